// Round 1
// baseline (1193.603 us; speedup 1.0000x reference)
//
#include <hip/hip_runtime.h>
#include <math.h>

#define BB 64
#define CCH 64
#define MMH 8192
#define SLICES 8
#define KSL (MMH / SLICES) /* 1024 */
#define TMZ 128
constexpr double EPSV = 1e-5;

// ---------------- K1: partial fp64 Gram + row sums ----------------
// grid: BB*SLICES blocks, 256 threads. Gpart/rspart live in d_out (overwritten by Z later).
__global__ __launch_bounds__(256, 2) void k1_partG(const float* __restrict__ x,
                                                   double* __restrict__ Gpart,
                                                   double* __restrict__ rspart) {
  __shared__ double xs[CCH][65];
  __shared__ double rred[CCH][4];
  const int tid = threadIdx.x;
  const int b = blockIdx.x / SLICES;
  const int s = blockIdx.x % SLICES;
  const int wv = tid >> 6;      // wave id 0..3
  const int lane = tid & 63;
  const int li = lane >> 3, lj = lane & 7;
  const int i0 = li * 8, j0 = lj * 8;
  const int rr = tid & 63, qq = tid >> 6;
  const float* xb = x + (size_t)b * CCH * MMH + (size_t)s * KSL;
  double acc[8][8];
#pragma unroll
  for (int a = 0; a < 8; ++a)
#pragma unroll
    for (int c = 0; c < 8; ++c) acc[a][c] = 0.0;
  double rsum = 0.0;
  for (int chunk = 0; chunk < KSL / 64; ++chunk) {
    const int c0 = chunk * 64;
#pragma unroll
    for (int k2 = 0; k2 < 16; ++k2) {
      int idx = k2 * 256 + tid;
      int r = idx >> 6, cc2 = idx & 63;
      xs[r][cc2] = (double)xb[(size_t)r * MMH + c0 + cc2];
    }
    __syncthreads();
#pragma unroll
    for (int j2 = 0; j2 < 16; ++j2) rsum += xs[rr][qq * 16 + j2];
    // each wave handles its own 16 columns of the chunk
    for (int tt = 0; tt < 16; ++tt) {
      const int t = wv * 16 + tt;
      double av[8], bv[8];
#pragma unroll
      for (int a = 0; a < 8; ++a) av[a] = xs[i0 + a][t];
#pragma unroll
      for (int c = 0; c < 8; ++c) bv[c] = xs[j0 + c][t];
#pragma unroll
      for (int a = 0; a < 8; ++a)
#pragma unroll
        for (int c = 0; c < 8; ++c) acc[a][c] += av[a] * bv[c];
    }
    __syncthreads();
  }
  // cross-wave reduction into xs (reused as G buffer)
  for (int w = 0; w < 4; ++w) {
    if (wv == w) {
      if (w == 0) {
#pragma unroll
        for (int a = 0; a < 8; ++a)
#pragma unroll
          for (int c = 0; c < 8; ++c) xs[i0 + a][j0 + c] = acc[a][c];
      } else {
#pragma unroll
        for (int a = 0; a < 8; ++a)
#pragma unroll
          for (int c = 0; c < 8; ++c) xs[i0 + a][j0 + c] += acc[a][c];
      }
    }
    __syncthreads();
  }
  double* gp = Gpart + ((size_t)b * SLICES + s) * (CCH * CCH);
  for (int k = tid; k < CCH * CCH; k += 256) gp[k] = xs[k >> 6][k & 63];
  rred[rr][qq] = rsum;
  __syncthreads();
  if (tid < CCH) {
    rspart[((size_t)b * SLICES + s) * CCH + tid] =
        rred[tid][0] + rred[tid][1] + rred[tid][2] + rred[tid][3];
  }
}

// ---------------- K2: reduce partials -> cov (f32 copy), mu, rho/clip (fp64) ----------------
__global__ __launch_bounds__(256) void k2_reduce(const double* __restrict__ Gpart,
                                                 const double* __restrict__ rspart,
                                                 float* __restrict__ cov32,
                                                 float* __restrict__ mu32,
                                                 double* __restrict__ scal) {
  __shared__ double muS[CCH];
  __shared__ double red[256];
  const int tid = threadIdx.x;
  const int b = blockIdx.x;
  if (tid < CCH) {
    double r = 0.0;
    for (int s = 0; s < SLICES; ++s) r += rspart[((size_t)b * SLICES + s) * CCH + tid];
    double mu = r / (double)MMH;
    muS[tid] = mu;
    mu32[b * CCH + tid] = (float)mu;
  }
  __syncthreads();
  double t1 = 0.0, t2 = 0.0;
  for (int k = tid; k < CCH * CCH; k += 256) {
    int i = k >> 6, j = k & 63;
    double g = 0.0;
    for (int s = 0; s < SLICES; ++s) g += Gpart[((size_t)b * SLICES + s) * (CCH * CCH) + k];
    double cv = g / (double)MMH - muS[i] * muS[j];
    cov32[(size_t)b * CCH * CCH + k] = (float)cv;
    if (i == j) t1 += cv;
    t2 += cv * cv;
  }
  red[tid] = t1;
  __syncthreads();
  for (int st = 128; st > 0; st >>= 1) {
    if (tid < st) red[tid] += red[tid + st];
    __syncthreads();
  }
  double T1 = red[0];
  __syncthreads();
  red[tid] = t2;
  __syncthreads();
  for (int st = 128; st > 0; st >>= 1) {
    if (tid < st) red[tid] += red[tid + st];
    __syncthreads();
  }
  double T2 = red[0];
  if (tid == 0) {
    double num = ((double)(MMH - 2) / (double)MMH) * T2 + T1 * T1;
    double den = (double)(MMH + 2) * (T2 - T1 * T1 / (double)CCH);
    double r = num / den;
    double rho = (r < 1.0) ? r : 1.0;
    scal[b * 4 + 0] = rho;
    scal[b * 4 + 1] = T1 / (double)CCH;  // alpha0
    scal[b * 4 + 2] = 1.0 - rho;
    scal[b * 4 + 3] = (r >= 1.0) ? 1.0 : 0.0;  // clipped
  }
}

// ---------------- K3: parallel cyclic Jacobi (fp32) on pre-shrinkage cov ----------------
__global__ __launch_bounds__(256) void k3_jacobi(const float* __restrict__ cov32,
                                                 const double* __restrict__ scal,
                                                 float* __restrict__ V32,
                                                 double* __restrict__ lamp,
                                                 int* __restrict__ perm) {
  __shared__ float A[CCH][CCH + 1];
  __shared__ float V[CCH][CCH + 1];
  __shared__ float cs[32], sn[32];
  __shared__ int pr[32], qr[32];
  __shared__ float lamS[CCH];
  __shared__ int idxS[CCH];
  __shared__ float offred[256];
  const int tid = threadIdx.x;
  const int b = blockIdx.x;
  const double rho = scal[b * 4 + 0];
  const double alpha0 = scal[b * 4 + 1];
  const int clipped = (scal[b * 4 + 3] != 0.0);
  if (clipped) {
    // cov' is exactly alpha*I; numpy SVD returns U = I. Identity basis, equal eigenvalues.
    if (tid < CCH) {
      lamp[b * CCH + tid] = alpha0 + EPSV;
      perm[b * CCH + tid] = tid;
    }
    return;
  }
  for (int k = tid; k < CCH * CCH; k += 256) {
    int i = k >> 6, j = k & 63;
    A[i][j] = cov32[(size_t)b * CCH * CCH + k];
    V[i][j] = (i == j) ? 1.0f : 0.0f;
  }
  __syncthreads();
  for (int sweep = 0; sweep < 12; ++sweep) {
    // off-diagonal norm^2 for early exit
    float off = 0.0f;
    for (int k = tid; k < CCH * CCH; k += 256) {
      int i = k >> 6, j = k & 63;
      if (i != j) {
        float v = A[i][j];
        off += v * v;
      }
    }
    offred[tid] = off;
    __syncthreads();
    for (int st = 128; st > 0; st >>= 1) {
      if (tid < st) offred[tid] += offred[tid + st];
      __syncthreads();
    }
    float off2 = offred[0];
    __syncthreads();
    if (off2 < 3e-10f) break;
    for (int r = 0; r < 63; ++r) {
      if (tid < 32) {
        int p, q;
        if (tid == 0) {
          p = 63;
          q = r;
        } else {
          p = (r + tid) % 63;
          q = (r - tid + 63) % 63;
        }
        if (p > q) {
          int t3 = p;
          p = q;
          q = t3;
        }
        float app = A[p][p], aqq = A[q][q], apq = A[p][q];
        float c, s;
        if (fabsf(apq) < 1e-30f) {
          c = 1.0f;
          s = 0.0f;
        } else {
          float theta = (aqq - app) / (2.0f * apq);
          float tt = 1.0f / (fabsf(theta) + sqrtf(theta * theta + 1.0f));
          if (theta < 0.0f) tt = -tt;
          c = 1.0f / sqrtf(1.0f + tt * tt);
          s = tt * c;
        }
        cs[tid] = c;
        sn[tid] = s;
        pr[tid] = p;
        qr[tid] = q;
      }
      __syncthreads();
      // row phase: wave w at iter it handles pair k = it*4+w, col t = lane (conflict-free)
#pragma unroll
      for (int it = 0; it < 8; ++it) {
        int idx = it * 256 + tid;
        int k = idx >> 6, t = idx & 63;
        int p = pr[k], q = qr[k];
        float c = cs[k], s = sn[k];
        float ap = A[p][t], aq = A[q][t];
        A[p][t] = c * ap - s * aq;
        A[q][t] = s * ap + c * aq;
      }
      __syncthreads();
      // column phase (+ eigenvector accumulation V <- V * R^T)
#pragma unroll
      for (int it = 0; it < 8; ++it) {
        int idx = it * 256 + tid;
        int k = idx >> 6, t = idx & 63;
        int p = pr[k], q = qr[k];
        float c = cs[k], s = sn[k];
        float ap = A[t][p], aq = A[t][q];
        A[t][p] = c * ap - s * aq;
        A[t][q] = s * ap + c * aq;
        float vp = V[t][p], vq = V[t][q];
        V[t][p] = c * vp - s * vq;
        V[t][q] = s * vp + c * vq;
      }
      __syncthreads();
    }
  }
  if (tid < CCH) lamS[tid] = A[tid][tid];
  __syncthreads();
  // stable rank sort, descending
  if (tid < CCH) {
    float my = lamS[tid];
    int pos = 0;
    for (int k = 0; k < CCH; ++k) {
      float v = lamS[k];
      if (v > my || (v == my && k < tid)) pos++;
    }
    idxS[pos] = tid;
  }
  __syncthreads();
  if (tid < CCH) {
    double lam = (double)lamS[idxS[tid]];
    lamp[b * CCH + tid] = rho * alpha0 + (1.0 - rho) * lam + EPSV;  // shrunk eigenvalue, sorted desc
    perm[b * CCH + tid] = idxS[tid];
  }
  for (int k = tid; k < CCH * CCH; k += 256) V32[(size_t)b * CCH * CCH + k] = V[k >> 6][k & 63];
}

// ---------------- K5: counter = argmax over cross-batch conds ----------------
__global__ void k5_counter(const double* __restrict__ lamp, int* __restrict__ counterI) {
  __shared__ unsigned long long red[64];
  const int tid = threadIdx.x;
  unsigned long long mask = 0ull;
  if (tid < BB) {
    double tot = 0.0;
    for (int j = 0; j < CCH; ++j) tot += lamp[tid * CCH + j];
    double thr = (1.0 - EPSV) * tot;
    double cum = 0.0;
    for (int j = 0; j < CCH; ++j) {
      double lj = lamp[tid * CCH + j];
      cum += lj;
      if (cum >= thr || lj <= EPSV) mask |= (1ull << j);
    }
  }
  red[tid] = mask;
  __syncthreads();
  for (int st = 32; st > 0; st >>= 1) {
    if (tid < st) red[tid] |= red[tid + st];
    __syncthreads();
  }
  if (tid == 0) {
    unsigned long long m2 = red[0];
    *counterI = (m2 == 0ull) ? CCH : (__ffsll((long long)m2) - 1);
  }
}

// ---------------- K6: S_hat = V diag(w) V^T (w=0 for excluded tail), smu = S_hat*mu ----------------
__global__ __launch_bounds__(256) void k6_shat(const float* __restrict__ V32,
                                               const double* __restrict__ lamp,
                                               const int* __restrict__ perm,
                                               const double* __restrict__ scal,
                                               const float* __restrict__ mu32,
                                               const int* __restrict__ counterI,
                                               float* __restrict__ S32,
                                               float* __restrict__ smu32) {
  __shared__ float Vs[CCH][CCH + 1];
  __shared__ float w[CCH];
  __shared__ float muS[CCH];
  __shared__ float y[CCH];
  const int tid = threadIdx.x;
  const int b = blockIdx.x;
  const int counter = *counterI;
  const double alpha0 = scal[b * 4 + 1];
  const int clipped = (scal[b * 4 + 3] != 0.0);
  if (clipped) {
    const float wd = (float)(1.0 / sqrt(alpha0 + EPSV));
    for (int k = tid; k < CCH * CCH; k += 256) {
      int i = k >> 6, j = k & 63;
      S32[(size_t)b * CCH * CCH + k] = (i == j && i < counter) ? wd : 0.0f;
    }
    if (tid < CCH) smu32[b * CCH + tid] = (tid < counter) ? wd * mu32[b * CCH + tid] : 0.0f;
    return;
  }
  if (tid < CCH) {
    w[tid] = 0.0f;
    muS[tid] = mu32[b * CCH + tid];
  }
  for (int k = tid; k < CCH * CCH; k += 256) Vs[k >> 6][k & 63] = V32[(size_t)b * CCH * CCH + k];
  __syncthreads();
  if (tid < CCH && tid < counter) {
    int col = perm[b * CCH + tid];
    w[col] = (float)(1.0 / sqrt(lamp[b * CCH + tid]));
  }
  __syncthreads();
  if (tid < CCH) {
    float a2 = 0.0f;
    for (int k2 = 0; k2 < CCH; ++k2) a2 += Vs[k2][tid] * muS[k2];
    y[tid] = a2;  // y = V^T mu
  }
  __syncthreads();
  const int ti = tid >> 4, tj = tid & 15;
  const int i0 = ti * 4, j0 = tj * 4;
  float acc[4][4];
#pragma unroll
  for (int a = 0; a < 4; ++a)
#pragma unroll
    for (int c = 0; c < 4; ++c) acc[a][c] = 0.0f;
  for (int r = 0; r < CCH; ++r) {
    const float wr = w[r];
    float av[4], bv[4];
#pragma unroll
    for (int a = 0; a < 4; ++a) av[a] = Vs[i0 + a][r] * wr;
#pragma unroll
    for (int c = 0; c < 4; ++c) bv[c] = Vs[j0 + c][r];
#pragma unroll
    for (int a = 0; a < 4; ++a)
#pragma unroll
      for (int c = 0; c < 4; ++c) acc[a][c] += av[a] * bv[c];
  }
#pragma unroll
  for (int a = 0; a < 4; ++a)
#pragma unroll
    for (int c = 0; c < 4; ++c)
      S32[(size_t)b * CCH * CCH + (i0 + a) * CCH + (j0 + c)] = acc[a][c];
  if (tid < CCH) {
    float a3 = 0.0f;
    for (int r = 0; r < CCH; ++r) a3 += w[r] * Vs[tid][r] * y[r];
    smu32[b * CCH + tid] = a3;  // S_hat * mu
  }
}

// ---------------- K7: Z = S_hat * x - (S_hat*mu) * 1^T ----------------
__global__ __launch_bounds__(256) void k7_z(const float* __restrict__ x,
                                            const float* __restrict__ S32,
                                            const float* __restrict__ smu32,
                                            float* __restrict__ z) {
  __shared__ float Ss[CCH][CCH + 1];
  __shared__ float xsv[CCH][TMZ + 4];
  const int tid = threadIdx.x;
  const int b = blockIdx.y;
  const int t0 = blockIdx.x * TMZ;
  for (int k = tid; k < CCH * CCH; k += 256) Ss[k >> 6][k & 63] = S32[(size_t)b * CCH * CCH + k];
  const float* xb = x + (size_t)b * CCH * MMH + t0;
  for (int k = tid; k < CCH * (TMZ / 4); k += 256) {
    int r = k >> 5;      // TMZ/4 = 32 float4 per row
    int cq = k & 31;
    float4 v = *(const float4*)(xb + (size_t)r * MMH + cq * 4);
    *(float4*)&xsv[r][cq * 4] = v;
  }
  __syncthreads();
  const int tr = tid >> 4, tc = tid & 15;
  const int i0 = tr * 4, c0 = tc * 8;
  float acc[4][8];
#pragma unroll
  for (int i = 0; i < 4; ++i)
#pragma unroll
    for (int j = 0; j < 8; ++j) acc[i][j] = 0.0f;
  for (int k = 0; k < CCH; ++k) {
    float s0 = Ss[i0][k], s1 = Ss[i0 + 1][k], s2 = Ss[i0 + 2][k], s3 = Ss[i0 + 3][k];
    float xv[8];
#pragma unroll
    for (int j = 0; j < 8; ++j) xv[j] = xsv[k][c0 + j];
#pragma unroll
    for (int j = 0; j < 8; ++j) {
      acc[0][j] += s0 * xv[j];
      acc[1][j] += s1 * xv[j];
      acc[2][j] += s2 * xv[j];
      acc[3][j] += s3 * xv[j];
    }
  }
#pragma unroll
  for (int i = 0; i < 4; ++i) {
    float sm = smu32[b * CCH + i0 + i];
    float4 o0 = make_float4(acc[i][0] - sm, acc[i][1] - sm, acc[i][2] - sm, acc[i][3] - sm);
    float4 o1 = make_float4(acc[i][4] - sm, acc[i][5] - sm, acc[i][6] - sm, acc[i][7] - sm);
    float4* zp = (float4*)(z + ((size_t)b * CCH + i0 + i) * MMH + t0 + c0);
    zp[0] = o0;
    zp[1] = o1;
  }
}

extern "C" void kernel_launch(void* const* d_in, const int* in_sizes, int n_in,
                              void* d_out, int out_size, void* d_ws, size_t ws_size,
                              hipStream_t stream) {
  (void)in_sizes;
  (void)n_in;
  (void)out_size;
  (void)ws_size;
  const float* x = (const float*)d_in[0];
  float* z = (float*)d_out;
  // Gram partials live inside d_out (17MB << 128MB); fully overwritten by Z in K7.
  double* Gpart = (double*)d_out;
  double* rspart = (double*)((char*)d_out + 16777216);
  char* ws = (char*)d_ws;
  float* cov32 = (float*)(ws + 0);          // 1,048,576
  float* mu32 = (float*)(ws + 1048576);     // 16,384
  double* scal = (double*)(ws + 1064960);   // 2,048
  float* V32 = (float*)(ws + 1067008);      // 1,048,576
  double* lamp = (double*)(ws + 2115584);   // 32,768
  int* perm = (int*)(ws + 2148352);         // 16,384
  int* cnt = (int*)(ws + 2164736);          // 16
  float* S32 = (float*)(ws + 2164752);      // 1,048,576
  float* smu32 = (float*)(ws + 3213328);    // 16,384  (total ~3.1 MB)

  k1_partG<<<dim3(BB * SLICES), dim3(256), 0, stream>>>(x, Gpart, rspart);
  k2_reduce<<<dim3(BB), dim3(256), 0, stream>>>(Gpart, rspart, cov32, mu32, scal);
  k3_jacobi<<<dim3(BB), dim3(256), 0, stream>>>(cov32, scal, V32, lamp, perm);
  k5_counter<<<dim3(1), dim3(64), 0, stream>>>(lamp, cnt);
  k6_shat<<<dim3(BB), dim3(256), 0, stream>>>(V32, lamp, perm, scal, mu32, cnt, S32, smu32);
  k7_z<<<dim3(MMH / TMZ, BB), dim3(256), 0, stream>>>(x, S32, smu32, z);
}

// Round 2
// 495.750 us; speedup vs baseline: 2.4077x; 2.4077x over previous
//
#include <hip/hip_runtime.h>
#include <math.h>

#define BB 64
#define CCH 64
#define MMH 8192
#define SLICES 8
#define KSL (MMH / SLICES) /* 1024 */
#define TMZ 128
constexpr double EPSV = 1e-5;

// ---------------- K1: partial fp64 Gram + row sums ----------------
__global__ __launch_bounds__(256, 2) void k1_partG(const float* __restrict__ x,
                                                   double* __restrict__ Gpart,
                                                   double* __restrict__ rspart) {
  __shared__ double xs[CCH][65];
  __shared__ double rred[CCH][4];
  const int tid = threadIdx.x;
  const int b = blockIdx.x / SLICES;
  const int s = blockIdx.x % SLICES;
  const int wv = tid >> 6;
  const int lane = tid & 63;
  const int li = lane >> 3, lj = lane & 7;
  const int i0 = li * 8, j0 = lj * 8;
  const int rr = tid & 63, qq = tid >> 6;
  const float* xb = x + (size_t)b * CCH * MMH + (size_t)s * KSL;
  double acc[8][8];
#pragma unroll
  for (int a = 0; a < 8; ++a)
#pragma unroll
    for (int c = 0; c < 8; ++c) acc[a][c] = 0.0;
  double rsum = 0.0;
  for (int chunk = 0; chunk < KSL / 64; ++chunk) {
    const int c0 = chunk * 64;
#pragma unroll
    for (int k2 = 0; k2 < 16; ++k2) {
      int idx = k2 * 256 + tid;
      int r = idx >> 6, cc2 = idx & 63;
      xs[r][cc2] = (double)xb[(size_t)r * MMH + c0 + cc2];
    }
    __syncthreads();
#pragma unroll
    for (int j2 = 0; j2 < 16; ++j2) rsum += xs[rr][qq * 16 + j2];
    for (int tt = 0; tt < 16; ++tt) {
      const int t = wv * 16 + tt;
      double av[8], bv[8];
#pragma unroll
      for (int a = 0; a < 8; ++a) av[a] = xs[i0 + a][t];
#pragma unroll
      for (int c = 0; c < 8; ++c) bv[c] = xs[j0 + c][t];
#pragma unroll
      for (int a = 0; a < 8; ++a)
#pragma unroll
        for (int c = 0; c < 8; ++c) acc[a][c] += av[a] * bv[c];
    }
    __syncthreads();
  }
  for (int w = 0; w < 4; ++w) {
    if (wv == w) {
      if (w == 0) {
#pragma unroll
        for (int a = 0; a < 8; ++a)
#pragma unroll
          for (int c = 0; c < 8; ++c) xs[i0 + a][j0 + c] = acc[a][c];
      } else {
#pragma unroll
        for (int a = 0; a < 8; ++a)
#pragma unroll
          for (int c = 0; c < 8; ++c) xs[i0 + a][j0 + c] += acc[a][c];
      }
    }
    __syncthreads();
  }
  double* gp = Gpart + ((size_t)b * SLICES + s) * (CCH * CCH);
  for (int k = tid; k < CCH * CCH; k += 256) gp[k] = xs[k >> 6][k & 63];
  rred[rr][qq] = rsum;
  __syncthreads();
  if (tid < CCH) {
    rspart[((size_t)b * SLICES + s) * CCH + tid] =
        rred[tid][0] + rred[tid][1] + rred[tid][2] + rred[tid][3];
  }
}

// ---------------- K2: reduce partials -> cov (f32), mu, rho/clip (fp64) ----------------
__global__ __launch_bounds__(256) void k2_reduce(const double* __restrict__ Gpart,
                                                 const double* __restrict__ rspart,
                                                 float* __restrict__ cov32,
                                                 float* __restrict__ mu32,
                                                 double* __restrict__ scal) {
  __shared__ double muS[CCH];
  __shared__ double red[256];
  const int tid = threadIdx.x;
  const int b = blockIdx.x;
  if (tid < CCH) {
    double r = 0.0;
    for (int s = 0; s < SLICES; ++s) r += rspart[((size_t)b * SLICES + s) * CCH + tid];
    double mu = r / (double)MMH;
    muS[tid] = mu;
    mu32[b * CCH + tid] = (float)mu;
  }
  __syncthreads();
  double t1 = 0.0, t2 = 0.0;
  for (int k = tid; k < CCH * CCH; k += 256) {
    int i = k >> 6, j = k & 63;
    double g = 0.0;
    for (int s = 0; s < SLICES; ++s) g += Gpart[((size_t)b * SLICES + s) * (CCH * CCH) + k];
    double cv = g / (double)MMH - muS[i] * muS[j];
    cov32[(size_t)b * CCH * CCH + k] = (float)cv;
    if (i == j) t1 += cv;
    t2 += cv * cv;
  }
  red[tid] = t1;
  __syncthreads();
  for (int st = 128; st > 0; st >>= 1) {
    if (tid < st) red[tid] += red[tid + st];
    __syncthreads();
  }
  double T1 = red[0];
  __syncthreads();
  red[tid] = t2;
  __syncthreads();
  for (int st = 128; st > 0; st >>= 1) {
    if (tid < st) red[tid] += red[tid + st];
    __syncthreads();
  }
  double T2 = red[0];
  if (tid == 0) {
    double num = ((double)(MMH - 2) / (double)MMH) * T2 + T1 * T1;
    double den = (double)(MMH + 2) * (T2 - T1 * T1 / (double)CCH);
    double r = num / den;
    double rho = (r < 1.0) ? r : 1.0;
    scal[b * 4 + 0] = rho;
    scal[b * 4 + 1] = T1 / (double)CCH;  // alpha0
    scal[b * 4 + 2] = 1.0 - rho;
    scal[b * 4 + 3] = (r >= 1.0) ? 1.0 : 0.0;  // clipped
  }
}

// ---------------- K3: Newton-Schulz invsqrt + repeated-squaring deflation ----------------
// S_hat = (cov')^{-1/2} - w63 * v63 v63^T.  All GEMM operands are symmetric
// (polynomials in cov), so operand rows are read in place of columns.
__device__ __forceinline__ void gemm_acc(const float (*A)[64], const float (*B)[64],
                                         int i0, int j0, float acc[4][4]) {
#pragma unroll
  for (int a = 0; a < 4; ++a)
#pragma unroll
    for (int c = 0; c < 4; ++c) acc[a][c] = 0.f;
#pragma unroll 4
  for (int k = 0; k < 64; ++k) {
    const float4 av = *(const float4*)&A[k][i0];
    const float4 bv = *(const float4*)&B[k][j0];
    const float aa[4] = {av.x, av.y, av.z, av.w};
    const float bb[4] = {bv.x, bv.y, bv.z, bv.w};
#pragma unroll
    for (int a = 0; a < 4; ++a)
#pragma unroll
      for (int c = 0; c < 4; ++c) acc[a][c] = fmaf(aa[a], bb[c], acc[a][c]);
  }
}

__global__ __launch_bounds__(256) void k3_ns(const float* __restrict__ cov32,
                                             const double* __restrict__ scal,
                                             const float* __restrict__ mu32,
                                             float* __restrict__ S32,
                                             float* __restrict__ smu32) {
  __shared__ float As[64][64];
  __shared__ float Xs[64][64];
  __shared__ float Bs[64][64];
  __shared__ float red[64];
  __shared__ float vS[64];
  __shared__ float yS[64];
  __shared__ float muS[64];
  const int tid = threadIdx.x;
  const int b = blockIdx.x;
  const double rho = scal[b * 4 + 0];
  const double alpha0 = scal[b * 4 + 1];
  const int clipped = (scal[b * 4 + 3] != 0.0);
  float* Sg = S32 + (size_t)b * 4096;
  if (clipped) {
    // cov' = (alpha+eps)I exactly; numpy SVD returns U=I; exclude e_63.
    const float wd = (float)(1.0 / sqrt(alpha0 + EPSV));
    for (int k = tid; k < 4096; k += 256) {
      int i = k >> 6, j = k & 63;
      Sg[k] = (i == j && i < 63) ? wd : 0.f;
    }
    if (tid < 64) smu32[b * 64 + tid] = (tid < 63) ? wd * mu32[b * 64 + tid] : 0.f;
    return;
  }
  const float cc = (float)(alpha0 + EPSV);
  const float orhoc = (float)((1.0 - rho) / (alpha0 + EPSV));
  const float dtermc = (float)((rho * alpha0 + EPSV) / (alpha0 + EPSV));
  // load A; X0 = 1.5I - 0.5T,  T = orhoc*A + dtermc*I (spectrum in [0.8,1.2])
  for (int k = tid; k < 4096; k += 256) {
    int i = k >> 6, j = k & 63;
    float a = cov32[(size_t)b * 4096 + k];
    As[i][j] = a;
    float t = orhoc * a + ((i == j) ? dtermc : 0.f);
    Xs[i][j] = ((i == j) ? 1.5f : 0.f) - 0.5f * t;
  }
  if (tid < 64) muS[tid] = mu32[b * 64 + tid];
  __syncthreads();
  const int i0 = (tid >> 4) << 2, j0 = (tid & 15) << 2;
  float acc[4][4];
  // ---- Newton-Schulz: X <- 0.5*X*(3I - T*X*X), 5 iterations (6 effective) ----
  for (int it = 0; it < 5; ++it) {
    gemm_acc(Xs, Xs, i0, j0, acc);  // U = X*X
#pragma unroll
    for (int a = 0; a < 4; ++a)
#pragma unroll
      for (int c = 0; c < 4; ++c) Bs[i0 + a][j0 + c] = acc[a][c];
    __syncthreads();
    // V = T*U = orhoc*(A*U) + dtermc*U  (in-place on Bs, deferred write)
    gemm_acc(As, Bs, i0, j0, acc);
    float bold[4][4];
#pragma unroll
    for (int a = 0; a < 4; ++a)
#pragma unroll
      for (int c = 0; c < 4; ++c) bold[a][c] = Bs[i0 + a][j0 + c];
    __syncthreads();
#pragma unroll
    for (int a = 0; a < 4; ++a)
#pragma unroll
      for (int c = 0; c < 4; ++c) Bs[i0 + a][j0 + c] = orhoc * acc[a][c] + dtermc * bold[a][c];
    __syncthreads();
    // X <- 1.5X - 0.5*(X*V)  (deferred in-place on X)
    gemm_acc(Xs, Bs, i0, j0, acc);
    float xold[4][4];
#pragma unroll
    for (int a = 0; a < 4; ++a)
#pragma unroll
      for (int c = 0; c < 4; ++c) xold[a][c] = Xs[i0 + a][j0 + c];
    __syncthreads();
#pragma unroll
    for (int a = 0; a < 4; ++a)
#pragma unroll
      for (int c = 0; c < 4; ++c) Xs[i0 + a][j0 + c] = 1.5f * xold[a][c] - 0.5f * acc[a][c];
    __syncthreads();
  }
  // ---- Gershgorin upper bound sigma (column sums; A symmetric) ----
  if (tid < 64) {
    float s = 0.f;
    for (int j = 0; j < 64; ++j) {
      float v = As[j][tid];
      s += (j == tid) ? v : fabsf(v);
    }
    red[tid] = s;
  }
  __syncthreads();
  float sig = 0.f;
  for (int j = 0; j < 64; ++j) sig = fmaxf(sig, red[j]);
  __syncthreads();
  // ---- P = sigma*I - A; 18 trace-normalized in-place squarings -> v63 v63^T ----
#pragma unroll
  for (int a = 0; a < 4; ++a)
#pragma unroll
    for (int c = 0; c < 4; ++c) {
      int i = i0 + a, j = j0 + c;
      Bs[i][j] = ((i == j) ? sig : 0.f) - As[i][j];
    }
  if (i0 == j0)
    red[tid >> 4] = Bs[i0][j0] + Bs[i0 + 1][j0 + 1] + Bs[i0 + 2][j0 + 2] + Bs[i0 + 3][j0 + 3];
  __syncthreads();
  for (int s5 = 0; s5 < 18; ++s5) {
    float t = 0.f;
    for (int j = 0; j < 16; ++j) t += red[j];
    float scale = 1.f / (t * t);
    gemm_acc(Bs, Bs, i0, j0, acc);
    __syncthreads();
#pragma unroll
    for (int a = 0; a < 4; ++a)
#pragma unroll
      for (int c = 0; c < 4; ++c) Bs[i0 + a][j0 + c] = acc[a][c] * scale;
    if (i0 == j0)
      red[tid >> 4] = (acc[0][0] + acc[1][1] + acc[2][2] + acc[3][3]) * scale;
    __syncthreads();
  }
  // ---- extract v (row jstar), Rayleigh lambda63, assemble S ----
  int jstar = 0;
  float best = -1.f;
  for (int j = 0; j < 64; ++j) {
    float d = Bs[j][j];
    if (d > best) {
      best = d;
      jstar = j;
    }
  }
  if (tid < 64) vS[tid] = Bs[jstar][tid];
  __syncthreads();
  if (tid < 64) {
    float s = 0.f;
    for (int j = 0; j < 64; ++j) s += As[j][tid] * vS[j];  // y = A*v (col reads, A sym)
    yS[tid] = s;
  }
  __syncthreads();
  float vy = 0.f, vv = 0.f;
  for (int j = 0; j < 64; ++j) {
    vy += vS[j] * yS[j];
    vv += vS[j] * vS[j];
  }
  float lam = vy / vv;
  float lampr = (float)(rho * alpha0 + EPSV) + (float)(1.0 - rho) * lam;
  float w = 1.f / sqrtf(lampr);
  float invsqc = 1.f / sqrtf(cc);
  float invn = 1.f / sqrtf(vv);
  for (int k = tid; k < 4096; k += 256) {
    int i = k >> 6, j = k & 63;
    float vi = vS[i] * invn, vj = vS[j] * invn;
    Sg[k] = Xs[i][j] * invsqc - w * vi * vj;
  }
  if (tid < 64) {
    float sm = 0.f, vmu = 0.f;
    for (int j = 0; j < 64; ++j) {
      sm += Xs[j][tid] * muS[j];  // X row tid (sym) dot mu
      vmu += vS[j] * muS[j];
    }
    smu32[b * 64 + tid] = sm * invsqc - w * (vS[tid] * invn) * (vmu * invn);
  }
}

// ---------------- K7: Z = S_hat * x - (S_hat*mu) * 1^T ----------------
__global__ __launch_bounds__(256) void k7_z(const float* __restrict__ x,
                                            const float* __restrict__ S32,
                                            const float* __restrict__ smu32,
                                            float* __restrict__ z) {
  __shared__ float Ss[CCH][CCH + 1];
  __shared__ float xsv[CCH][TMZ + 4];
  const int tid = threadIdx.x;
  const int b = blockIdx.y;
  const int t0 = blockIdx.x * TMZ;
  for (int k = tid; k < CCH * CCH; k += 256) Ss[k >> 6][k & 63] = S32[(size_t)b * CCH * CCH + k];
  const float* xb = x + (size_t)b * CCH * MMH + t0;
  for (int k = tid; k < CCH * (TMZ / 4); k += 256) {
    int r = k >> 5;
    int cq = k & 31;
    float4 v = *(const float4*)(xb + (size_t)r * MMH + cq * 4);
    *(float4*)&xsv[r][cq * 4] = v;
  }
  __syncthreads();
  const int tr = tid >> 4, tc = tid & 15;
  const int i0 = tr * 4, c0 = tc * 8;
  float acc[4][8];
#pragma unroll
  for (int i = 0; i < 4; ++i)
#pragma unroll
    for (int j = 0; j < 8; ++j) acc[i][j] = 0.0f;
  for (int k = 0; k < CCH; ++k) {
    float s0 = Ss[i0][k], s1 = Ss[i0 + 1][k], s2 = Ss[i0 + 2][k], s3 = Ss[i0 + 3][k];
    float xv[8];
#pragma unroll
    for (int j = 0; j < 8; ++j) xv[j] = xsv[k][c0 + j];
#pragma unroll
    for (int j = 0; j < 8; ++j) {
      acc[0][j] += s0 * xv[j];
      acc[1][j] += s1 * xv[j];
      acc[2][j] += s2 * xv[j];
      acc[3][j] += s3 * xv[j];
    }
  }
#pragma unroll
  for (int i = 0; i < 4; ++i) {
    float sm = smu32[b * CCH + i0 + i];
    float4 o0 = make_float4(acc[i][0] - sm, acc[i][1] - sm, acc[i][2] - sm, acc[i][3] - sm);
    float4 o1 = make_float4(acc[i][4] - sm, acc[i][5] - sm, acc[i][6] - sm, acc[i][7] - sm);
    float4* zp = (float4*)(z + ((size_t)b * CCH + i0 + i) * MMH + t0 + c0);
    zp[0] = o0;
    zp[1] = o1;
  }
}

extern "C" void kernel_launch(void* const* d_in, const int* in_sizes, int n_in,
                              void* d_out, int out_size, void* d_ws, size_t ws_size,
                              hipStream_t stream) {
  (void)in_sizes;
  (void)n_in;
  (void)out_size;
  (void)ws_size;
  const float* x = (const float*)d_in[0];
  float* z = (float*)d_out;
  // Gram partials live inside d_out (17MB << 128MB); fully overwritten by Z in K7.
  double* Gpart = (double*)d_out;
  double* rspart = (double*)((char*)d_out + 16777216);
  char* ws = (char*)d_ws;
  float* cov32 = (float*)(ws + 0);          // 1,048,576
  float* mu32 = (float*)(ws + 1048576);     // 16,384
  double* scal = (double*)(ws + 1064960);   // 2,048
  float* S32 = (float*)(ws + 2164752);      // 1,048,576
  float* smu32 = (float*)(ws + 3213328);    // 16,384

  k1_partG<<<dim3(BB * SLICES), dim3(256), 0, stream>>>(x, Gpart, rspart);
  k2_reduce<<<dim3(BB), dim3(256), 0, stream>>>(Gpart, rspart, cov32, mu32, scal);
  k3_ns<<<dim3(BB), dim3(256), 0, stream>>>(cov32, scal, mu32, S32, smu32);
  k7_z<<<dim3(MMH / TMZ, BB), dim3(256), 0, stream>>>(x, S32, smu32, z);
}

// Round 3
// 344.699 us; speedup vs baseline: 3.4627x; 1.4382x over previous
//
#include <hip/hip_runtime.h>
#include <math.h>

#define BB 64
#define CCH 64
#define MMH 8192
#define SLICES 8
#define KSL 1024 /* K per k1 block */
#define KCH 128  /* K per LDS chunk in k1 */
#define TMZ 128
constexpr double EPSV = 1e-5;

typedef __attribute__((ext_vector_type(8))) short bf16x8;
typedef __attribute__((ext_vector_type(8))) unsigned short u16x8;
typedef __attribute__((ext_vector_type(16))) float floatx16;

__device__ __forceinline__ unsigned short rne_bf16(float f) {
  unsigned u = __float_as_uint(f);
  unsigned r = (u + 0x7fffu + ((u >> 16) & 1u)) >> 16;
  return (unsigned short)r;
}
__device__ __forceinline__ float bf16_to_f(unsigned short h) {
  return __uint_as_float(((unsigned)h) << 16);
}

// ---------------- K1: bf16-split MFMA partial Gram + row sums ----------------
// x = h1+h2+h3 (bf16 splits, exact fp32 residuals). G = sum of 6 split products
// via mfma_f32_32x32x16_bf16, fp32 accum (error ~1e-7 rel, << ref fp32 noise).
// Any k-permutation in the A/B fragment mapping cancels in a Gram (same perm
// both sides); C/D mapping is the HW-verified one.
__global__ __launch_bounds__(256, 2) void k1_partG(const float* __restrict__ x,
                                                   float* __restrict__ Gpart,
                                                   float* __restrict__ rspart) {
  __shared__ unsigned short h1[64][KCH + 8], h2[64][KCH + 8], h3[64][KCH + 8];
  __shared__ float rred[64][4];
  const int tid = threadIdx.x;
  const int b = blockIdx.x / SLICES;
  const int s = blockIdx.x % SLICES;
  const int row = tid >> 2;
  const int seg = (tid & 3) * 32;
  const int wv = tid >> 6;
  const int lane = tid & 63;
  const int rw = wv >> 1, cw = wv & 1;
  const int mrow = 32 * rw + (lane & 31);
  const int ncol = 32 * cw + (lane & 31);
  const int koff = (lane >> 5) * 8;
  const float* xb = x + (size_t)b * CCH * MMH + (size_t)s * KSL;
  floatx16 acc = {};
  float rsum = 0.f;
  for (int c = 0; c < KSL / KCH; ++c) {
    const float* xp = xb + (size_t)row * MMH + c * KCH + seg;
    float v[32];
#pragma unroll
    for (int q = 0; q < 8; ++q) {
      float4 t = *(const float4*)(xp + 4 * q);
      v[4 * q] = t.x;
      v[4 * q + 1] = t.y;
      v[4 * q + 2] = t.z;
      v[4 * q + 3] = t.w;
    }
#pragma unroll
    for (int o = 0; o < 32; ++o) rsum += v[o];
#pragma unroll
    for (int g = 0; g < 4; ++g) {
      u16x8 a1, a2, a3;
#pragma unroll
      for (int j = 0; j < 8; ++j) {
        float f = v[8 * g + j];
        unsigned short q1 = rne_bf16(f);
        float r1 = f - bf16_to_f(q1);
        unsigned short q2 = rne_bf16(r1);
        float r2 = r1 - bf16_to_f(q2);
        unsigned short q3 = rne_bf16(r2);
        a1[j] = q1;
        a2[j] = q2;
        a3[j] = q3;
      }
      *(u16x8*)&h1[row][seg + 8 * g] = a1;
      *(u16x8*)&h2[row][seg + 8 * g] = a2;
      *(u16x8*)&h3[row][seg + 8 * g] = a3;
    }
    __syncthreads();
#pragma unroll
    for (int ks = 0; ks < KCH / 16; ++ks) {
      const int kk = ks * 16 + koff;
      bf16x8 A1 = *(const bf16x8*)&h1[mrow][kk];
      bf16x8 A2 = *(const bf16x8*)&h2[mrow][kk];
      bf16x8 A3 = *(const bf16x8*)&h3[mrow][kk];
      bf16x8 B1 = *(const bf16x8*)&h1[ncol][kk];
      bf16x8 B2 = *(const bf16x8*)&h2[ncol][kk];
      bf16x8 B3 = *(const bf16x8*)&h3[ncol][kk];
      acc = __builtin_amdgcn_mfma_f32_32x32x16_bf16(A1, B1, acc, 0, 0, 0);
      acc = __builtin_amdgcn_mfma_f32_32x32x16_bf16(A1, B2, acc, 0, 0, 0);
      acc = __builtin_amdgcn_mfma_f32_32x32x16_bf16(A2, B1, acc, 0, 0, 0);
      acc = __builtin_amdgcn_mfma_f32_32x32x16_bf16(A2, B2, acc, 0, 0, 0);
      acc = __builtin_amdgcn_mfma_f32_32x32x16_bf16(A1, B3, acc, 0, 0, 0);
      acc = __builtin_amdgcn_mfma_f32_32x32x16_bf16(A3, B1, acc, 0, 0, 0);
    }
    __syncthreads();
  }
  // C/D: col=lane&31, row=(reg&3)+8*(reg>>2)+4*(lane>>5)  [HW-verified]
  float* gp = Gpart + ((size_t)(b * SLICES + s)) * 4096;
#pragma unroll
  for (int r = 0; r < 16; ++r) {
    int row32 = (r & 3) + 8 * (r >> 2) + 4 * (lane >> 5);
    gp[(32 * rw + row32) * 64 + 32 * cw + (lane & 31)] = acc[r];
  }
  rred[row][tid & 3] = rsum;
  __syncthreads();
  if (tid < 64) {
    rspart[((size_t)(b * SLICES + s)) * 64 + tid] =
        rred[tid][0] + rred[tid][1] + rred[tid][2] + rred[tid][3];
  }
}

// ---------------- K2: fp64 reduce partials -> cov (f32), mu, rho/clip ----------------
__global__ __launch_bounds__(256) void k2_reduce(const float* __restrict__ Gpart,
                                                 const float* __restrict__ rspart,
                                                 float* __restrict__ cov32,
                                                 float* __restrict__ mu32,
                                                 double* __restrict__ scal) {
  __shared__ double muS[64];
  __shared__ double red[256];
  const int tid = threadIdx.x;
  const int b = blockIdx.x;
  if (tid < 64) {
    double r = 0.0;
    for (int s = 0; s < SLICES; ++s) r += (double)rspart[((size_t)(b * SLICES + s)) * 64 + tid];
    double mu = r / (double)MMH;
    muS[tid] = mu;
    mu32[b * 64 + tid] = (float)mu;
  }
  __syncthreads();
  const int base = tid * 16;
  const int i = tid >> 2;
  double g[16];
#pragma unroll
  for (int e = 0; e < 16; ++e) g[e] = 0.0;
  for (int s = 0; s < SLICES; ++s) {
    const float* gp = Gpart + ((size_t)(b * SLICES + s)) * 4096 + base;
#pragma unroll
    for (int q = 0; q < 4; ++q) {
      float4 t = *(const float4*)(gp + 4 * q);
      g[4 * q] += (double)t.x;
      g[4 * q + 1] += (double)t.y;
      g[4 * q + 2] += (double)t.z;
      g[4 * q + 3] += (double)t.w;
    }
  }
  double t1 = 0.0, t2 = 0.0;
#pragma unroll
  for (int e = 0; e < 16; ++e) {
    int j = (base + e) & 63;
    double cv = g[e] / (double)MMH - muS[i] * muS[j];
    cov32[(size_t)b * 4096 + base + e] = (float)cv;
    if (i == j) t1 += cv;
    t2 += cv * cv;
  }
  red[tid] = t1;
  __syncthreads();
  for (int st = 128; st > 0; st >>= 1) {
    if (tid < st) red[tid] += red[tid + st];
    __syncthreads();
  }
  double T1 = red[0];
  __syncthreads();
  red[tid] = t2;
  __syncthreads();
  for (int st = 128; st > 0; st >>= 1) {
    if (tid < st) red[tid] += red[tid + st];
    __syncthreads();
  }
  double T2 = red[0];
  if (tid == 0) {
    double num = ((double)(MMH - 2) / (double)MMH) * T2 + T1 * T1;
    double den = (double)(MMH + 2) * (T2 - T1 * T1 / (double)CCH);
    double r = num / den;
    double rho = (r < 1.0) ? r : 1.0;
    scal[b * 4 + 0] = rho;
    scal[b * 4 + 1] = T1 / (double)CCH;
    scal[b * 4 + 2] = 1.0 - rho;
    scal[b * 4 + 3] = (r >= 1.0) ? 1.0 : 0.0;
  }
}

// ---------------- K3: two concurrent roles per batch ----------------
// role 0: Newton-Schulz X=T^{-1/2} (4 iters) -> SxG = X*invsqc, smuA = invsqc*X*mu
// role 1: repeated squaring of sigma*I - A -> v63 (normalized), w, v'mu
__device__ __forceinline__ void gemm_acc(const float (*A)[64], const float (*B)[64],
                                         int i0, int j0, float acc[4][4]) {
#pragma unroll
  for (int a = 0; a < 4; ++a)
#pragma unroll
    for (int c = 0; c < 4; ++c) acc[a][c] = 0.f;
#pragma unroll 4
  for (int k = 0; k < 64; ++k) {
    const float4 av = *(const float4*)&A[k][i0];
    const float4 bv = *(const float4*)&B[k][j0];
    const float aa[4] = {av.x, av.y, av.z, av.w};
    const float bb[4] = {bv.x, bv.y, bv.z, bv.w};
#pragma unroll
    for (int a = 0; a < 4; ++a)
#pragma unroll
      for (int c = 0; c < 4; ++c) acc[a][c] = fmaf(aa[a], bb[c], acc[a][c]);
  }
}

__global__ __launch_bounds__(256) void k3_eig(const float* __restrict__ cov32,
                                              const double* __restrict__ scal,
                                              const float* __restrict__ mu32,
                                              float* __restrict__ SxG,
                                              float* __restrict__ smuA,
                                              float* __restrict__ vS,
                                              float* __restrict__ wvm) {
  __shared__ float As[64][64];
  __shared__ float Xs[64][64];
  __shared__ float Bs[64][64];
  __shared__ float red[64];
  __shared__ float vSh[64];
  __shared__ float ySh[64];
  __shared__ float muS[64];
  const int tid = threadIdx.x;
  const int b = blockIdx.x & 63;
  const int role = blockIdx.x >> 6;
  const double rho = scal[b * 4 + 0];
  const double alpha0 = scal[b * 4 + 1];
  const int clipped = (scal[b * 4 + 3] != 0.0);
  const float invsqc = (float)(1.0 / sqrt(alpha0 + EPSV));
  const int i0 = (tid >> 4) << 2, j0 = (tid & 15) << 2;
  float acc[4][4];
  if (tid < 64) muS[tid] = mu32[b * 64 + tid];

  if (role == 0) {
    if (clipped) {
      for (int k = tid; k < 4096; k += 256) {
        int i = k >> 6, j = k & 63;
        SxG[(size_t)b * 4096 + k] = (i == j) ? invsqc : 0.f;
      }
      if (tid < 64) smuA[b * 64 + tid] = invsqc * muS[tid];
      return;
    }
    const float orhoc = (float)((1.0 - rho) / (alpha0 + EPSV));
    const float dtermc = (float)((rho * alpha0 + EPSV) / (alpha0 + EPSV));
    for (int k = tid; k < 4096; k += 256) {
      int i = k >> 6, j = k & 63;
      float a = cov32[(size_t)b * 4096 + k];
      As[i][j] = a;
      float t = orhoc * a + ((i == j) ? dtermc : 0.f);
      Xs[i][j] = ((i == j) ? 1.5f : 0.f) - 0.5f * t;
    }
    __syncthreads();
    for (int it = 0; it < 4; ++it) {
      gemm_acc(Xs, Xs, i0, j0, acc);  // U = X*X
#pragma unroll
      for (int a = 0; a < 4; ++a)
#pragma unroll
        for (int c = 0; c < 4; ++c) Bs[i0 + a][j0 + c] = acc[a][c];
      __syncthreads();
      gemm_acc(As, Bs, i0, j0, acc);  // A*U
      float bold[4][4];
#pragma unroll
      for (int a = 0; a < 4; ++a)
#pragma unroll
        for (int c = 0; c < 4; ++c) bold[a][c] = Bs[i0 + a][j0 + c];
      __syncthreads();
#pragma unroll
      for (int a = 0; a < 4; ++a)
#pragma unroll
        for (int c = 0; c < 4; ++c) Bs[i0 + a][j0 + c] = orhoc * acc[a][c] + dtermc * bold[a][c];
      __syncthreads();
      gemm_acc(Xs, Bs, i0, j0, acc);  // X*V
      float xold[4][4];
#pragma unroll
      for (int a = 0; a < 4; ++a)
#pragma unroll
        for (int c = 0; c < 4; ++c) xold[a][c] = Xs[i0 + a][j0 + c];
      __syncthreads();
#pragma unroll
      for (int a = 0; a < 4; ++a)
#pragma unroll
        for (int c = 0; c < 4; ++c) Xs[i0 + a][j0 + c] = 1.5f * xold[a][c] - 0.5f * acc[a][c];
      __syncthreads();
    }
    for (int k = tid; k < 4096; k += 256) SxG[(size_t)b * 4096 + k] = Xs[k >> 6][k & 63] * invsqc;
    if (tid < 64) {
      float sm = 0.f;
      for (int j = 0; j < 64; ++j) sm += Xs[j][tid] * muS[j];  // X sym
      smuA[b * 64 + tid] = sm * invsqc;
    }
  } else {
    if (clipped) {
      if (tid < 64) vS[b * 64 + tid] = (tid == 63) ? 1.f : 0.f;
      if (tid == 0) {
        wvm[b * 2] = invsqc;
        wvm[b * 2 + 1] = mu32[b * 64 + 63];
      }
      return;
    }
    for (int k = tid; k < 4096; k += 256) As[k >> 6][k & 63] = cov32[(size_t)b * 4096 + k];
    __syncthreads();
    if (tid < 64) {
      float s = 0.f;
      for (int j = 0; j < 64; ++j) {
        float v = As[j][tid];
        s += (j == tid) ? v : fabsf(v);
      }
      red[tid] = s;
    }
    __syncthreads();
    float sig = 0.f;
    for (int j = 0; j < 64; ++j) sig = fmaxf(sig, red[j]);
    __syncthreads();
#pragma unroll
    for (int a = 0; a < 4; ++a)
#pragma unroll
      for (int c = 0; c < 4; ++c) {
        int i = i0 + a, j = j0 + c;
        Bs[i][j] = ((i == j) ? sig : 0.f) - As[i][j];
      }
    if (i0 == j0)
      red[tid >> 4] = Bs[i0][j0] + Bs[i0 + 1][j0 + 1] + Bs[i0 + 2][j0 + 2] + Bs[i0 + 3][j0 + 3];
    __syncthreads();
    for (int s5 = 0; s5 < 18; ++s5) {
      float t = 0.f;
      for (int j = 0; j < 16; ++j) t += red[j];
      float scale = 1.f / (t * t);
      gemm_acc(Bs, Bs, i0, j0, acc);
      __syncthreads();
#pragma unroll
      for (int a = 0; a < 4; ++a)
#pragma unroll
        for (int c = 0; c < 4; ++c) Bs[i0 + a][j0 + c] = acc[a][c] * scale;
      if (i0 == j0)
        red[tid >> 4] = (acc[0][0] + acc[1][1] + acc[2][2] + acc[3][3]) * scale;
      __syncthreads();
    }
    int jstar = 0;
    float best = -1.f;
    for (int j = 0; j < 64; ++j) {
      float d = Bs[j][j];
      if (d > best) {
        best = d;
        jstar = j;
      }
    }
    if (tid < 64) vSh[tid] = Bs[jstar][tid];
    __syncthreads();
    if (tid < 64) {
      float s = 0.f;
      for (int j = 0; j < 64; ++j) s += As[j][tid] * vSh[j];  // A sym
      ySh[tid] = s;
    }
    __syncthreads();
    float vy = 0.f, vv = 0.f;
    for (int j = 0; j < 64; ++j) {
      vy += vSh[j] * ySh[j];
      vv += vSh[j] * vSh[j];
    }
    float lam = vy / vv;
    float lampr = (float)(rho * alpha0 + EPSV) + (float)(1.0 - rho) * lam;
    float w = 1.f / sqrtf(lampr);
    float invn = 1.f / sqrtf(vv);
    if (tid < 64) vS[b * 64 + tid] = vSh[tid] * invn;
    if (tid == 0) {
      float vmu = 0.f;
      for (int j = 0; j < 64; ++j) vmu += vSh[j] * invn * muS[j];
      wvm[b * 2] = w;
      wvm[b * 2 + 1] = vmu;
    }
  }
}

// ---------------- K7: Z = (SxG - w v v^T) x - smu 1^T  (rank-1 folded in) ----------------
__global__ __launch_bounds__(256) void k7_z(const float* __restrict__ x,
                                            const float* __restrict__ SxG,
                                            const float* __restrict__ smuA,
                                            const float* __restrict__ vS,
                                            const float* __restrict__ wvm,
                                            float* __restrict__ z) {
  __shared__ float Ss[64][68];
  __shared__ float xsv[64][192];  // 16 chunks of 12 floats (8 used) -> 2-way banks
  __shared__ float vsh[64];
  __shared__ float smsh[64];
  const int tid = threadIdx.x;
  const int b = blockIdx.y;
  const int t0 = blockIdx.x * TMZ;
  {
    const float* sp = SxG + (size_t)b * 4096 + tid * 16;
    int i = tid >> 2, js = (tid & 3) * 16;
#pragma unroll
    for (int q = 0; q < 4; ++q) *(float4*)&Ss[i][js + 4 * q] = *(const float4*)(sp + 4 * q);
  }
  if (tid < 64) vsh[tid] = vS[b * 64 + tid];
  const float* xb = x + (size_t)b * CCH * MMH + t0;
  {
    int r = tid >> 2, cs = (tid & 3) * 32;
#pragma unroll
    for (int q = 0; q < 4; ++q) {
      int c = cs + q * 8;
      float4 p0 = *(const float4*)(xb + (size_t)r * MMH + c);
      float4 p1 = *(const float4*)(xb + (size_t)r * MMH + c + 4);
      int tcq = c >> 3;
      *(float4*)&xsv[r][12 * tcq] = p0;
      *(float4*)&xsv[r][12 * tcq + 4] = p1;
    }
  }
  __syncthreads();
  const float w = wvm[b * 2], vmu = wvm[b * 2 + 1];
  {
    int i = tid >> 2, js = (tid & 3) * 16;
    float wvi = w * vsh[i];
#pragma unroll
    for (int e = 0; e < 16; ++e) Ss[i][js + e] -= wvi * vsh[js + e];
  }
  if (tid < 64) smsh[tid] = smuA[b * 64 + tid] - w * vsh[tid] * vmu;
  __syncthreads();
  const int tr = tid >> 4, tc = tid & 15;
  const int i0 = tr * 4;
  float acc[4][8];
#pragma unroll
  for (int i = 0; i < 4; ++i)
#pragma unroll
    for (int j = 0; j < 8; ++j) acc[i][j] = 0.f;
  for (int k = 0; k < 64; ++k) {
    float4 sv = *(const float4*)&Ss[k][i0];  // S column (symmetric)
    float4 xa = *(const float4*)&xsv[k][12 * tc];
    float4 xc = *(const float4*)&xsv[k][12 * tc + 4];
    const float sa[4] = {sv.x, sv.y, sv.z, sv.w};
    const float xv[8] = {xa.x, xa.y, xa.z, xa.w, xc.x, xc.y, xc.z, xc.w};
#pragma unroll
    for (int i = 0; i < 4; ++i)
#pragma unroll
      for (int j = 0; j < 8; ++j) acc[i][j] = fmaf(sa[i], xv[j], acc[i][j]);
  }
#pragma unroll
  for (int i = 0; i < 4; ++i) {
    float sm = smsh[i0 + i];
    float4 o0 = make_float4(acc[i][0] - sm, acc[i][1] - sm, acc[i][2] - sm, acc[i][3] - sm);
    float4 o1 = make_float4(acc[i][4] - sm, acc[i][5] - sm, acc[i][6] - sm, acc[i][7] - sm);
    float4* zp = (float4*)(z + ((size_t)b * CCH + i0 + i) * MMH + t0 + tc * 8);
    zp[0] = o0;
    zp[1] = o1;
  }
}

extern "C" void kernel_launch(void* const* d_in, const int* in_sizes, int n_in,
                              void* d_out, int out_size, void* d_ws, size_t ws_size,
                              hipStream_t stream) {
  (void)in_sizes;
  (void)n_in;
  (void)out_size;
  (void)ws_size;
  const float* x = (const float*)d_in[0];
  float* z = (float*)d_out;
  // Gram partials live inside d_out (8.5 MB << 128 MB); overwritten by Z in K7.
  float* Gpart = (float*)d_out;                          // 64*8*4096*4 = 8,388,608
  float* rspart = (float*)((char*)d_out + 8388608);      // 64*8*64*4   = 131,072
  char* ws = (char*)d_ws;
  float* cov32 = (float*)(ws + 0);         // 1,048,576
  float* mu32 = (float*)(ws + 1048576);    // 16,384
  double* scal = (double*)(ws + 1064960);  // 2,048
  float* SxG = (float*)(ws + 1067008);     // 1,048,576
  float* smuA = (float*)(ws + 2115584);    // 16,384
  float* vS = (float*)(ws + 2131968);      // 16,384
  float* wvm = (float*)(ws + 2148352);     // 512

  k1_partG<<<dim3(BB * SLICES), dim3(256), 0, stream>>>(x, Gpart, rspart);
  k2_reduce<<<dim3(BB), dim3(256), 0, stream>>>(Gpart, rspart, cov32, mu32, scal);
  k3_eig<<<dim3(2 * BB), dim3(256), 0, stream>>>(cov32, scal, mu32, SxG, smuA, vS, wvm);
  k7_z<<<dim3(MMH / TMZ, BB), dim3(256), 0, stream>>>(x, SxG, smuA, vS, wvm, z);
}